// Round 1
// baseline (81.297 us; speedup 1.0000x reference)
//
#include <hip/hip_runtime.h>
#include <math.h>

// Problem constants (from reference): B=4, C=128, H=W=96, E=4, C8=16, scale=2
#define Bn 4
#define Cc 128
#define Hh 96
#define Ww 96
#define H2c 192
#define W2c 192

// Block = 192 threads (3 waves). Each block handles one (b, row-pair) where the
// two rows are y and y+2 (same y-parity). Thread t owns output column x = t for
// both rows. Weights are pre-mixed per pixel-class into LDS.
__global__ __launch_bounds__(192, 2) void meta_up_kernel(
    const float* __restrict__ x,      // [B,C,H,W]
    const float* __restrict__ wcomp,  // [E,16,128]
    const float* __restrict__ wexp,   // [E,128,16]
    const float* __restrict__ bw1,    // [64,3]
    const float* __restrict__ bb1,    // [64]
    const float* __restrict__ bw2,    // [64,64]
    const float* __restrict__ bb2,    // [64]
    const float* __restrict__ rw,     // [4,64]
    const float* __restrict__ rb,     // [4]
    const float* __restrict__ ow,     // [2,64]
    const float* __restrict__ ob,     // [2]
    float* __restrict__ out)          // [B,C,H2,W2]
{
    __shared__ __align__(16) float lWc[2 * 16 * 128];  // [pcx][o][c]
    __shared__ __align__(16) float lWe[2 * 128 * 16];  // [pcx][c][o]
    __shared__ float lh[2 * 64];
    __shared__ float lr[2 * 4];
    __shared__ float loff[2 * 2];

    const int tid = threadIdx.x;
    const int jb  = blockIdx.x;              // 0..95 : row-pair index
    const int b   = blockIdx.y;              // batch
    const int ybase = (jb & 1) + (jb >> 1) * 4;  // rows ybase, ybase+2 (same parity)
    const int py = ybase & 1;

    // ---------------- tiny MLP for the 2 classes of this y-parity ----------------
    // inp = (1/sc, ch, cw) with ch = py? +0.25 : -0.25, cw = pcx? +0.25 : -0.25
    if (tid < 128) {
        const int pcx = tid >> 6;
        const int jj  = tid & 63;
        const float i1 = py  ? 0.25f : -0.25f;
        const float i2 = pcx ? 0.25f : -0.25f;
        float h = bw1[jj*3+0]*0.5f + bw1[jj*3+1]*i1 + bw1[jj*3+2]*i2 + bb1[jj];
        lh[pcx*64 + jj] = fmaxf(h, 0.f);
    }
    __syncthreads();
    float h2v = 0.f;
    if (tid < 128) {
        const int pcx = tid >> 6;
        const int jj  = tid & 63;
        float s = bb2[jj];
        for (int i = 0; i < 64; ++i) s += bw2[jj*64+i] * lh[pcx*64+i];
        h2v = fmaxf(s, 0.f);
    }
    __syncthreads();
    if (tid < 128) {
        const int pcx = tid >> 6;
        const int jj  = tid & 63;
        lh[pcx*64 + jj] = h2v;
    }
    __syncthreads();
    if (tid < 12) {
        const int pcx = tid / 6;
        const int h   = tid % 6;
        if (h < 4) {
            float s = rb[h];
            for (int i = 0; i < 64; ++i) s += rw[h*64+i] * lh[pcx*64+i];
            lr[pcx*4 + h] = 1.f / (1.f + expf(-s));
        } else {
            const int d = h - 4;
            float s = ob[d];
            for (int i = 0; i < 64; ++i) s += ow[d*64+i] * lh[pcx*64+i];
            loff[pcx*2 + d] = s;
        }
    }
    __syncthreads();

    // ---------------- mix expert weights per class into LDS ----------------
    // wcomp flat: e*2048 + (o*128+c) ; wexp flat: e*2048 + (c*16+o)
    for (int idx = tid; idx < 2 * 2048; idx += 192) {
        const int pcx  = idx >> 11;
        const int rest = idx & 2047;
        const float r0 = lr[pcx*4+0], r1 = lr[pcx*4+1], r2 = lr[pcx*4+2], r3 = lr[pcx*4+3];
        lWc[idx] = r0*wcomp[0*2048+rest] + r1*wcomp[1*2048+rest]
                 + r2*wcomp[2*2048+rest] + r3*wcomp[3*2048+rest];
        lWe[idx] = r0*wexp[0*2048+rest] + r1*wexp[1*2048+rest]
                 + r2*wexp[2*2048+rest] + r3*wexp[3*2048+rest];
    }
    __syncthreads();

    // ---------------- per-thread sampling setup ----------------
    const int xg = tid;              // output column 0..191
    const int pc = xg & 1;
    const float oxv = loff[pc*2+0];
    const float oyv = loff[pc*2+1];
    const int ya = ybase, yb = ybase + 2;

    // ix = (x+0.5)/2 - 0.5 + off_x ; iy likewise
    const float ixf = 0.5f*(float)xg - 0.25f + oxv;
    const float x0f = floorf(ixf);
    const float tx  = ixf - x0f;
    const int   x0  = (int)x0f;

    const float iyaf = 0.5f*(float)ya - 0.25f + oyv;
    const float y0af = floorf(iyaf);
    const float tya  = iyaf - y0af;
    const int   y0a  = (int)y0af;

    const float iybf = 0.5f*(float)yb - 0.25f + oyv;
    const float y0bf = floorf(iybf);
    const float tyb  = iybf - y0bf;
    const int   y0b  = (int)y0bf;

    const bool vx0  = (x0   >= 0) && (x0   < Ww);
    const bool vx1  = (x0+1 >= 0) && (x0+1 < Ww);
    const bool vya0 = (y0a   >= 0) && (y0a   < Hh);
    const bool vya1 = (y0a+1 >= 0) && (y0a+1 < Hh);
    const bool vyb0 = (y0b   >= 0) && (y0b   < Hh);
    const bool vyb1 = (y0b+1 >= 0) && (y0b+1 < Hh);

    const int xc0 = min(max(x0,   0), Ww-1);
    const int xc1 = min(max(x0+1, 0), Ww-1);
    const int ra0 = min(max(y0a,   0), Hh-1) * Ww;
    const int ra1 = min(max(y0a+1, 0), Hh-1) * Ww;
    const int rb0 = min(max(y0b,   0), Hh-1) * Ww;
    const int rb1 = min(max(y0b+1, 0), Hh-1) * Ww;

    // masked bilinear weights (validity folded in)
    const float wa00 = (1.f-tx)*(1.f-tya) * ((vx0&&vya0)?1.f:0.f);
    const float wa01 = tx      *(1.f-tya) * ((vx1&&vya0)?1.f:0.f);
    const float wa10 = (1.f-tx)*tya       * ((vx0&&vya1)?1.f:0.f);
    const float wa11 = tx      *tya       * ((vx1&&vya1)?1.f:0.f);
    const float wb00 = (1.f-tx)*(1.f-tyb) * ((vx0&&vyb0)?1.f:0.f);
    const float wb01 = tx      *(1.f-tyb) * ((vx1&&vyb0)?1.f:0.f);
    const float wb10 = (1.f-tx)*tyb       * ((vx0&&vyb1)?1.f:0.f);
    const float wb11 = tx      *tyb       * ((vx1&&vyb1)?1.f:0.f);

    const float* xb = x + (size_t)b * Cc * Hh * Ww;

    // ---------------- pass 1: compress  comp = Wc_mix . fea ----------------
    float comp_a[16], comp_b[16];
    #pragma unroll
    for (int o = 0; o < 16; ++o) { comp_a[o] = 0.f; comp_b[o] = 0.f; }

    for (int c0 = 0; c0 < Cc; c0 += 4) {
        float fa[4], fb[4];
        #pragma unroll
        for (int q = 0; q < 4; ++q) {
            const float* p = xb + (size_t)(c0 + q) * (Hh*Ww);
            const float t00 = p[ra0 + xc0];
            const float t01 = p[ra0 + xc1];
            const float t10 = p[ra1 + xc0];
            const float t11 = p[ra1 + xc1];
            fa[q] = wa00*t00 + wa01*t01 + wa10*t10 + wa11*t11;
            const float s00 = p[rb0 + xc0];
            const float s01 = p[rb0 + xc1];
            const float s10 = p[rb1 + xc0];
            const float s11 = p[rb1 + xc1];
            fb[q] = wb00*s00 + wb01*s01 + wb10*s10 + wb11*s11;
        }
        #pragma unroll
        for (int o = 0; o < 16; ++o) {
            const float4 w = *reinterpret_cast<const float4*>(&lWc[pc*2048 + o*128 + c0]);
            comp_a[o] += w.x*fa[0] + w.y*fa[1] + w.z*fa[2] + w.w*fa[3];
            comp_b[o] += w.x*fb[0] + w.y*fb[1] + w.z*fb[2] + w.w*fb[3];
        }
    }

    // ---------------- pass 2: expand + residual + store ----------------
    for (int c0 = 0; c0 < Cc; c0 += 4) {
        #pragma unroll
        for (int q = 0; q < 4; ++q) {
            const int c = c0 + q;
            const float* p = xb + (size_t)c * (Hh*Ww);
            const float t00 = p[ra0 + xc0];
            const float t01 = p[ra0 + xc1];
            const float t10 = p[ra1 + xc0];
            const float t11 = p[ra1 + xc1];
            float acc_a = wa00*t00 + wa01*t01 + wa10*t10 + wa11*t11;  // fea0 residual
            const float s00 = p[rb0 + xc0];
            const float s01 = p[rb0 + xc1];
            const float s10 = p[rb1 + xc0];
            const float s11 = p[rb1 + xc1];
            float acc_b = wb00*s00 + wb01*s01 + wb10*s10 + wb11*s11;
            #pragma unroll
            for (int og = 0; og < 4; ++og) {
                const float4 w = *reinterpret_cast<const float4*>(&lWe[pc*2048 + c*16 + og*4]);
                acc_a += w.x*comp_a[og*4+0] + w.y*comp_a[og*4+1]
                       + w.z*comp_a[og*4+2] + w.w*comp_a[og*4+3];
                acc_b += w.x*comp_b[og*4+0] + w.y*comp_b[og*4+1]
                       + w.z*comp_b[og*4+2] + w.w*comp_b[og*4+3];
            }
            out[((size_t)(b*Cc + c) * H2c + ya) * W2c + xg] = acc_a;
            out[((size_t)(b*Cc + c) * H2c + yb) * W2c + xg] = acc_b;
        }
    }
}

extern "C" void kernel_launch(void* const* d_in, const int* in_sizes, int n_in,
                              void* d_out, int out_size, void* d_ws, size_t ws_size,
                              hipStream_t stream) {
    const float* x     = (const float*)d_in[0];
    const float* wcomp = (const float*)d_in[1];
    const float* wexp  = (const float*)d_in[2];
    const float* bw1   = (const float*)d_in[3];
    const float* bb1   = (const float*)d_in[4];
    const float* bw2   = (const float*)d_in[5];
    const float* bb2   = (const float*)d_in[6];
    const float* rw    = (const float*)d_in[7];
    const float* rb    = (const float*)d_in[8];
    const float* ow    = (const float*)d_in[9];
    const float* ob    = (const float*)d_in[10];
    // d_in[11] = scale (int, ==2) : baked into the kernel constants.
    float* out = (float*)d_out;

    dim3 grid(96, Bn, 1);   // 96 row-pairs x 4 batches
    meta_up_kernel<<<grid, 192, 0, stream>>>(x, wcomp, wexp, bw1, bb1, bw2, bb2,
                                             rw, rb, ow, ob, out);
}